// Round 7
// baseline (1828.350 us; speedup 1.0000x reference)
//
#include <hip/hip_runtime.h>
#include <math.h>

// Problem constants: B=32, T=64, N=128, D=64, E=5.  Time chunked: TC=16, 4 chunks.
// Workspace layout (float element offsets)
constexpr size_t WS_VV  = 1024;
constexpr size_t WS_TOT = 2048;
constexpr size_t WS_RS  = 8192;                  // 262144
constexpr size_t WS_WH  = 270336;                // 3*128*64*64 = 1572864 (Wr|Wu|Wc h-part)
constexpr size_t WS_WX  = 1843200;               // 3*128*65*64 = 1597440
constexpr size_t WS_BF  = 3440640;               // 3*128*64
constexpr size_t WS_H   = 3465216;               // 262144 (recurrent state; MALL-coherent)
constexpr size_t WS_CH  = 3727360;               // 262144 (combH exchange; MALL-coherent)
constexpr size_t WS_CX  = 3989504;               // 128*512*65 = 4259840   [n][b*16+tl][65]
constexpr size_t WS_GXR = 8249344;               // 128*16*32*64 = 4194304 [n][tl][b][o]
constexpr size_t WS_GXU = 12443648;
constexpr size_t WS_CXC = 16637952;
constexpr size_t WS_FLG = 20832256;              // flags: cfl[256] | hfl2[4096] (uint32)
// end = 20836608 floats = 79.5 MiB

__device__ __forceinline__ float sigm(float x){ return 1.f/(1.f+expf(-x)); }

// MALL-coherent (agent-scope relaxed => sc0 sc1, no cache maintenance) 8B ld/st
__device__ __forceinline__ float2 ld2_mall(const float* p){
  union { unsigned long long u; float2 f; } cv;
  cv.u = __hip_atomic_load((const unsigned long long*)p, __ATOMIC_RELAXED,
                           __HIP_MEMORY_SCOPE_AGENT);
  return cv.f;
}
__device__ __forceinline__ void st2_mall(float* p, float a, float b){
  union { unsigned long long u; float2 f; } cv;
  cv.f = make_float2(a, b);
  __hip_atomic_store((unsigned long long*)p, cv.u, __ATOMIC_RELAXED,
                     __HIP_MEMORY_SCOPE_AGENT);
}
__device__ __forceinline__ unsigned ldflag(const unsigned* p){
  return __hip_atomic_load(p, __ATOMIC_RELAXED, __HIP_MEMORY_SCOPE_AGENT);
}
__device__ __forceinline__ void stflag(unsigned* p, unsigned v){
  __hip_atomic_store(p, v, __ATOMIC_RELAXED, __HIP_MEMORY_SCOPE_AGENT);
}

// ---------------- vv = relu(vpe@W1+b1)@W2+b2 ----------------
__global__ void k_vv(const float* __restrict__ vpe, const float* __restrict__ W1,
                     const float* __restrict__ b1, const float* __restrict__ W2,
                     const float* __restrict__ b2, float* __restrict__ ws){
  int n = blockIdx.x, tid = threadIdx.x;
  __shared__ float hid[128];
  if (tid < 128){
    float acc = b1[tid];
    for (int k=0;k<768;k++) acc = fmaf(vpe[n*768+k], W1[k*128+tid], acc);
    hid[tid] = fmaxf(acc, 0.f);
  }
  __syncthreads();
  if (tid < 5){
    float acc = b2[tid];
    for (int h=0;h<128;h++) acc = fmaf(hid[h], W2[h*5+tid], acc);
    ws[WS_VV + n*5 + tid] = acc;
  }
}

// ---------------- fold per-node weights: Wn = sum_e vv[n,e]*W[e] ----------------
__global__ void k_fold(const float* __restrict__ Wr, const float* __restrict__ Wu,
                       const float* __restrict__ Wc, const float* __restrict__ br,
                       const float* __restrict__ bu, const float* __restrict__ bc,
                       float* __restrict__ ws){
  int bid = blockIdx.x; int g = bid>>7; int n = bid&127;
  const float* W  = (g==0)?Wr:(g==1)?Wu:Wc;
  const float* bb = (g==0)?br:(g==1)?bu:bc;
  float v[5];
#pragma unroll
  for (int e=0;e<5;e++) v[e] = ws[WS_VV + n*5 + e];
  for (int idx=threadIdx.x; idx<129*64; idx+=256){
    int i = idx>>6, o = idx&63;
    float a = 0.f;
#pragma unroll
    for (int e=0;e<5;e++) a = fmaf(v[e], W[(e*129+i)*64+o], a);
    if (i < 65) ws[WS_WX + (size_t)(g*128+n)*4160 + i*64 + o] = a;
    else        ws[WS_WH + (size_t)(g*128+n)*4096 + (i-65)*64 + o] = a;
  }
  if (threadIdx.x < 64){
    int o = threadIdx.x; float a = 0.f;
#pragma unroll
    for (int e=0;e<5;e++) a = fmaf(v[e], bb[e*64+o], a);
    ws[WS_BF + (g*128+n)*64 + o] = a;
  }
}

// ---------------- tot[b,n] = sum_t mask ----------------
__global__ void k_tot(const float* __restrict__ mask, float* __restrict__ ws){
  int id = blockIdx.x*256 + threadIdx.x;     // 4096
  int b = id>>7, n = id&127;
  float s = 0.f;
  for (int t=0;t<64;t++) s += mask[(b*64+t)*128 + n];
  ws[WS_TOT + b*128 + n] = s;
}

// ---------------- rs = 0.5*tanh(avg/(tot+1)) ----------------
__global__ void k_rs(const float* __restrict__ avg, float* __restrict__ ws){
  int id = blockIdx.x*256 + threadIdx.x;     // 262144
  int b = id>>13, n = id&127;
  float tot = ws[WS_TOT + b*128 + n];
  ws[WS_RS + id] = 0.5f * tanhf(avg[id] / (tot + 1.f));
}

// ---------------- P4a (per chunk): combX = adj @ xtilde, stored [i][b*16+tl][65] ----------------
__global__ __launch_bounds__(256) void p4a(const float* __restrict__ obs,
      const float* __restrict__ mask, const float* __restrict__ adjI,
      const float* __restrict__ rW, const int* __restrict__ lengths,
      float* __restrict__ ws, int c0){
  int rc = blockIdx.x;                 // b*16 + tl
  int b = rc>>4, tl = rc&15, t = c0 + tl;
  if (t >= lengths[b]) return;
  int rt = b*64 + t;
  __shared__ float xt[64*68];
  __shared__ float adjh[128*68];
  __shared__ float rs_l[128], m_l[128];
  int tid = threadIdx.x;
  if (tid < 128){ rs_l[tid] = ws[WS_RS + rt*128 + tid]; m_l[tid] = mask[rt*128 + tid]; }
  __syncthreads();
  int it = tid>>3, ft = tid&7, i0 = it*4, f0 = ft*8;
  float4 aL[4], aH[4]; float a64[4];
#pragma unroll
  for (int ii=0;ii<4;ii++){ aL[ii]=make_float4(0,0,0,0); aH[ii]=make_float4(0,0,0,0); a64[ii]=0.f; }
  for (int half=0; half<2; half++){
    __syncthreads();
    int j0 = half*64;
    for (int idx=tid; idx<4096; idx+=256){
      int jl = idx>>6, f = idx&63;
      xt[jl*68+f] = obs[(size_t)rt*8192 + (j0+jl)*64 + f];
    }
    if (tid < 64) xt[tid*68+64] = rs_l[j0+tid];
    for (int idx=tid; idx<8192; idx+=256){
      int i = idx>>6, jl = idx&63, j = j0+jl;
      float a;
      if (i == j) a = 1.f;
      else {
        int gi = i*128 + j;
        float dd = fabsf(rs_l[i] - rs_l[j]);
        a = adjI[gi] * (1.f - rW[gi]*dd) * m_l[i] * m_l[j];
      }
      adjh[i*68+jl] = a;
    }
    __syncthreads();
    for (int jb=0; jb<16; jb++){
      float4 av[4];
#pragma unroll
      for (int ii=0;ii<4;ii++) av[ii] = *(const float4*)&adjh[(i0+ii)*68 + jb*4];
#pragma unroll
      for (int jj=0;jj<4;jj++){
        int jl = jb*4 + jj;
        float4 xlo = *(const float4*)&xt[jl*68 + f0];
        float4 xhi = *(const float4*)&xt[jl*68 + f0 + 4];
        float xr = xt[jl*68 + 64];
#pragma unroll
        for (int ii=0;ii<4;ii++){
          float a = (jj==0)?av[ii].x:(jj==1)?av[ii].y:(jj==2)?av[ii].z:av[ii].w;
          aL[ii].x = fmaf(a, xlo.x, aL[ii].x); aL[ii].y = fmaf(a, xlo.y, aL[ii].y);
          aL[ii].z = fmaf(a, xlo.z, aL[ii].z); aL[ii].w = fmaf(a, xlo.w, aL[ii].w);
          aH[ii].x = fmaf(a, xhi.x, aH[ii].x); aH[ii].y = fmaf(a, xhi.y, aH[ii].y);
          aH[ii].z = fmaf(a, xhi.z, aH[ii].z); aH[ii].w = fmaf(a, xhi.w, aH[ii].w);
          a64[ii] = fmaf(a, xr, a64[ii]);
        }
      }
    }
  }
#pragma unroll
  for (int ii=0;ii<4;ii++){
    int i = i0 + ii;
    size_t base = WS_CX + (size_t)i*33280 + (size_t)rc*65 + f0;
    ws[base+0]=aL[ii].x; ws[base+1]=aL[ii].y; ws[base+2]=aL[ii].z; ws[base+3]=aL[ii].w;
    ws[base+4]=aH[ii].x; ws[base+5]=aH[ii].y; ws[base+6]=aH[ii].z; ws[base+7]=aH[ii].w;
    if (ft == 0) ws[WS_CX + (size_t)i*33280 + (size_t)rc*65 + 64] = a64[ii];
  }
}

// ---------------- P4b (per chunk): per-node GEMMs for x-part of gates (incl. bias) ----------------
__global__ __launch_bounds__(256) void p4b(const float* __restrict__ obs,
      const int* __restrict__ lengths, float* __restrict__ ws, int c0){
  int bid = blockIdx.x;                 // 1536 = 3 * 128 * 4
  int g = bid >> 9; int r2 = bid & 511; int n = r2 >> 2; int tile = r2 & 3;
  __shared__ float A[128*69];
  __shared__ float Wl[65*64];
  __shared__ float bl[64];
  __shared__ int slen[32];
  int tid = threadIdx.x;
  if (tid < 32) slen[tid] = lengths[tid];
  for (int idx=tid; idx<4160; idx+=256) Wl[idx] = ws[WS_WX + (size_t)(g*128+n)*4160 + idx];
  if (tid < 64) bl[tid] = ws[WS_BF + (g*128+n)*64 + tid];
  if (g < 2){
    const float* src = &ws[WS_CX + (size_t)n*33280 + (size_t)tile*8320];
    for (int idx=tid; idx<8320; idx+=256){
      int r = idx/65, f = idx - r*65;
      A[r*69+f] = src[idx];
    }
  } else {
    for (int idx=tid; idx<8320; idx+=256){
      int r = idx/65, f = idx - r*65;
      int grow = tile*128 + r;              // b*16+tl
      int gb = grow>>4, t = c0 + (grow&15);
      float v = (f < 64) ? obs[(size_t)(gb*64+t)*8192 + n*64 + f]
                         : ws[WS_RS + (gb*64+t)*128 + n];
      A[r*69+f] = v;
    }
  }
  __syncthreads();
  int rt8 = tid>>4, dq = tid&15;
  float4 acc[8];
#pragma unroll
  for (int rr=0;rr<8;rr++) acc[rr] = make_float4(0,0,0,0);
  for (int k=0;k<65;k++){
    float4 w = *(const float4*)&Wl[k*64 + dq*4];
#pragma unroll
    for (int rr=0;rr<8;rr++){
      float a = A[(rt8*8+rr)*69 + k];
      acc[rr].x = fmaf(a,w.x,acc[rr].x); acc[rr].y = fmaf(a,w.y,acc[rr].y);
      acc[rr].z = fmaf(a,w.z,acc[rr].z); acc[rr].w = fmaf(a,w.w,acc[rr].w);
    }
  }
  float4 b4 = *(const float4*)&bl[dq*4];
  float* dst = &ws[(g==0)?WS_GXR:(g==1)?WS_GXU:WS_CXC];
#pragma unroll
  for (int rr=0;rr<8;rr++){
    int grow = tile*128 + rt8*8 + rr;
    int gb = grow>>4, gtl = grow&15;
    if (c0 + gtl < slen[gb]){
      float4 o; o.x=acc[rr].x+b4.x; o.y=acc[rr].y+b4.y; o.z=acc[rr].z+b4.z; o.w=acc[rr].w+b4.w;
      *(float4*)&dst[((size_t)(n*16+gtl)*32 + gb)*64 + dq*4] = o;
    }
  }
}

// ---------------- Recurrent persistent kernel v7 (dataflow, per chunk) ----------------
// 512 blocks x 256 threads (any 2 fit one CU: A=60KB, B=57KB LDS => placement-safe).
//  bid<256: A-block (bA=bid>>3, slice sA=bid&7): per step, builds adj rows (adjI/rW
//    cached in LDS once), polls ONLY its batch's per-node flags hfl2[bA][0..127]
//    (2 cache lines), stages h, computes combH rows -> chbuf, stores cfl[bA*8+sA]=t+1.
//  bid>=256: B-block (nB, half hf): node weights in LDS; DATAFLOW passes: serves any
//    of its 16 batches whose combH is ready (per-batch done[] counters, per-thread
//    masks, out-of-order) -> no convoy; h fragments in registers; per-(batch,node)
//    flag hfl2[bb*128+nB]=t+1 after drain.
// All cross-block data via MALL (sc0 sc1); plain monotone flags; zero global atomics.
__global__ __launch_bounds__(256) void krec(const float* __restrict__ mask,
      const int* __restrict__ lengths, const float* __restrict__ adjI,
      const float* __restrict__ rWm, float* __restrict__ out, float* __restrict__ ws,
      int c0){
  unsigned* cfl  = (unsigned*)(ws + WS_FLG);        // [b*8+s]
  unsigned* hfl2 = ((unsigned*)(ws + WS_FLG)) + 256; // [b*128+n]
  const int bid = blockIdx.x, tid = threadIdx.x;
  __shared__ float smem[15104];                     // 60416 B (A uses all; B uses ~58KB)
  float* hbuf = &ws[WS_H];
  float* chb  = &ws[WS_CH];

  if (bid < 256){
    // ================= A-role =================
    const int bA = bid>>3, sA = bid&7, ns = sA*16;
    float* hs   = smem;            // 8192
    float* adjT = smem + 8192;     // [j][r] stride 20 -> 2560
    float* adjS = smem + 10752;    // [r][j] 2048 (cached adjI slice)
    float* rWS  = smem + 12800;    // 2048 (cached rarity_W slice)
    float* rs_l = smem + 14848;    // 128
    float* m_l  = smem + 14976;    // 128
    const int lenA = lengths[bA];
    if (c0 >= lenA) return;
    for (int idx=tid; idx<2048; idx+=256){
      int gi = (ns + (idx>>7))*128 + (idx&127);
      adjS[idx] = adjI[gi];
      rWS[idx]  = rWm[gi];
    }
    const int pr = tid>>4, fq = tid&15;   // row ns+pr, features fq*4..+4
    const int tEnd = (lenA < c0+16) ? lenA : (c0+16);
    __syncthreads();
    for (int t=c0; t<tEnd; t++){
      if (tid < 128) rs_l[tid] = ws[WS_RS + (size_t)(bA*64+t)*128 + tid];
      else           m_l[tid-128] = mask[(size_t)(bA*64+t)*128 + (tid-128)];
      __syncthreads();                              // rs/m ready
      for (int idx=tid; idx<2048; idx+=256){
        int r = idx>>7, j = idx&127, I = ns+r;
        float a;
        if (I == j) a = 1.f;
        else {
          float dd = fabsf(rs_l[I] - rs_l[j]);
          a = adjS[idx]*(1.f - rWS[idx]*dd)*m_l[I]*m_l[j];
        }
        adjT[j*20 + r] = a;
      }
      if (tid < 128){                               // poll own batch's node flags
        unsigned tgt = (unsigned)t; int guard = 0;
        while (ldflag(&hfl2[bA*128 + tid]) < tgt && ++guard < (1<<20))
          __builtin_amdgcn_s_sleep(1);
      }
      __syncthreads();                              // adjT + poll done
#pragma unroll
      for (int k2=0;k2<16;k2++){
        int p = tid + 256*k2;
        float2 v = ld2_mall(&hbuf[(size_t)bA*8192 + 2*p]);
        *(float2*)&hs[2*p] = v;
      }
      __syncthreads();                              // hs ready
      {
        float4 acc = make_float4(0,0,0,0);
#pragma unroll 4
        for (int j=0;j<128;j++){
          float aj = adjT[j*20 + pr];
          float4 h4 = *(const float4*)&hs[j*64 + fq*4];
          acc.x = fmaf(aj,h4.x,acc.x); acc.y = fmaf(aj,h4.y,acc.y);
          acc.z = fmaf(aj,h4.z,acc.z); acc.w = fmaf(aj,h4.w,acc.w);
        }
        float* cp = &chb[((size_t)bA*128 + ns + pr)*64 + fq*4];
        st2_mall(cp,   acc.x, acc.y);
        st2_mall(cp+2, acc.z, acc.w);
      }
      asm volatile("s_waitcnt vmcnt(0)" ::: "memory");
      __syncthreads();                              // all combH stores drained
      if (tid == 0)
        stflag(&cfl[bA*8 + sA], (unsigned)(t+1));
    }
  } else {
    // ================= B-role (dataflow) =================
    const int nB = (bid-256)>>1, hf = (bid-256)&1, b0 = hf*16;
    float* wR = smem;              // 4096
    float* wU = smem + 4096;
    float* wC = smem + 8192;
    float* cT = smem + 12288;      // [bi][k] stride 68 -> 1088
    float* hT = cT + 1088;         // [bi][k] stride 68 -> 1088
    int* done = (int*)(hT + 1088); // 16
    int* tgt  = done + 16;         // 16
    int* mword= tgt + 16;          // ready bitmask
    int* remw = mword + 1;         // remaining services
    for (int idx=tid; idx<3072; idx+=256){
      int g = idx>>10, r = idx&1023;
      *(float4*)&smem[g*4096 + r*4] =
        *(const float4*)&ws[WS_WH + (size_t)(g*128+nB)*4096 + (size_t)r*4];
    }
    const int bi = tid>>4, fq = tid&15;
    const int bb = b0 + bi;
    const int slenB = lengths[bb];
    const int sIdx = nB>>4;
    if (tid < 16){
      int sl = lengths[b0 + tid];
      int tg = sl - c0; if (tg < 0) tg = 0; if (tg > 16) tg = 16;
      tgt[tid] = tg; done[tid] = 0;
    }
    if (tid == 0) *remw = 0;
    __syncthreads();
    if (tid < 16) atomicAdd(remw, tgt[tid]);
    // persistent own-h fragment
    float4 hst;
    { const float* hp = &hbuf[((size_t)bb*128+nB)*64 + fq*4];
      float2 lo = ld2_mall(hp), hi = ld2_mall(hp+2);
      hst = make_float4(lo.x, lo.y, hi.x, hi.y); }
    __syncthreads();
    int rem = *remw;
    for (int pass=0; pass<6000 && rem>0; pass++){
      // speculative prefetch for this thread's batch at its next step
      int dn = done[bi];
      int t  = c0 + dn;
      bool maybe = (dn < tgt[bi]);
      float4 xr, xu, xc; float mv = 0.f;
      if (maybe){
        size_t gof = ((size_t)(nB*16+dn)*32 + bb)*64 + fq*4;
        xr = *(const float4*)&ws[WS_GXR + gof];
        xu = *(const float4*)&ws[WS_GXU + gof];
        xc = *(const float4*)&ws[WS_CXC + gof];
        mv = mask[(size_t)(bb*64+t)*128 + nB];
      }
      if (tid == 0) *mword = 0;
      __syncthreads();
      if (tid < 16){
        int d2 = done[tid];
        bool rdy = (d2 < tgt[tid]);
        if (rdy)
          rdy = (ldflag(&cfl[(b0+tid)*8 + sIdx]) >= (unsigned)(c0 + d2 + 1));
        if (rdy) atomicOr(mword, 1<<tid);
      }
      __syncthreads();
      unsigned msk = (unsigned)*mword;               // block-uniform
      if (msk == 0){ __builtin_amdgcn_s_sleep(4); continue; }
      const bool act = (msk>>bi) & 1;
      if (act){
        const float* cp = &chb[((size_t)bb*128 + nB)*64 + fq*4];
        float2 u = ld2_mall(cp), v = ld2_mall(cp+2);
        *(float4*)&cT[bi*68 + fq*4] = make_float4(u.x,u.y,v.x,v.y);
      }
      __syncthreads();                               // cT ready
      float4 uu, h1v; const bool ob = mv > 0.f;
      if (act){
        float4 ar = xr, au = xu;
#pragma unroll 4
        for (int k=0;k<64;k++){
          float cv = cT[bi*68 + k];
          float4 wr4 = *(const float4*)&wR[k*64 + fq*4];
          float4 wu4 = *(const float4*)&wU[k*64 + fq*4];
          ar.x = fmaf(cv,wr4.x,ar.x); ar.y = fmaf(cv,wr4.y,ar.y);
          ar.z = fmaf(cv,wr4.z,ar.z); ar.w = fmaf(cv,wr4.w,ar.w);
          au.x = fmaf(cv,wu4.x,au.x); au.y = fmaf(cv,wu4.y,au.y);
          au.z = fmaf(cv,wu4.z,au.z); au.w = fmaf(cv,wu4.w,au.w);
        }
        float4 rr;
        rr.x = sigm(ar.x); rr.y = sigm(ar.y); rr.z = sigm(ar.z); rr.w = sigm(ar.w);
        uu.x = sigm(au.x); uu.y = sigm(au.y); uu.z = sigm(au.z); uu.w = sigm(au.w);
        h1v.x = ob ? rr.x*hst.x : hst.x;
        h1v.y = ob ? rr.y*hst.y : hst.y;
        h1v.z = ob ? rr.z*hst.z : hst.z;
        h1v.w = ob ? rr.w*hst.w : hst.w;
        *(float4*)&hT[bi*68 + fq*4] = h1v;
      }
      __syncthreads();                               // hT ready
      if (act){
        float4 ac = xc;
#pragma unroll 4
        for (int k=0;k<64;k++){
          float hv = hT[bi*68 + k];
          float4 wc4 = *(const float4*)&wC[k*64 + fq*4];
          ac.x = fmaf(hv,wc4.x,ac.x); ac.y = fmaf(hv,wc4.y,ac.y);
          ac.z = fmaf(hv,wc4.z,ac.z); ac.w = fmaf(hv,wc4.w,ac.w);
        }
        float4 cd, h2;
        cd.x = tanhf(ac.x); cd.y = tanhf(ac.y); cd.z = tanhf(ac.z); cd.w = tanhf(ac.w);
        h2.x = ob ? (1.f-uu.x)*h1v.x + uu.x*cd.x : h1v.x;
        h2.y = ob ? (1.f-uu.y)*h1v.y + uu.y*cd.y : h1v.y;
        h2.z = ob ? (1.f-uu.z)*h1v.z + uu.z*cd.z : h1v.z;
        h2.w = ob ? (1.f-uu.w)*h1v.w + uu.w*cd.w : h1v.w;
        hst = h2;
        float* hp = &hbuf[((size_t)bb*128 + nB)*64 + fq*4];
        st2_mall(hp,   h2.x, h2.y);
        st2_mall(hp+2, h2.z, h2.w);
        if (t == slenB-1)
          *(float4*)&out[((size_t)bb*128 + nB)*64 + fq*4] = h2;
      }
      asm volatile("s_waitcnt vmcnt(0)" ::: "memory");
      __syncthreads();                               // all h stores drained
      if (tid < 16 && ((msk>>tid)&1)){
        done[tid] += 1;
        stflag(&hfl2[(b0+tid)*128 + nB], (unsigned)(c0 + done[tid]));
        atomicSub(remw, 1);
      }
      __syncthreads();
      rem = *remw;
    }
  }
}

extern "C" void kernel_launch(void* const* d_in, const int* in_sizes, int n_in,
                              void* d_out, int out_size, void* d_ws, size_t ws_size,
                              hipStream_t stream){
  const float* obs  = (const float*)d_in[0];
  const float* maskp= (const float*)d_in[2];
  const int*   lens = (const int*)d_in[5];
  const float* avg  = (const float*)d_in[6];
  const float* vpe  = (const float*)d_in[7];
  const float* rW   = (const float*)d_in[8];
  const float* adjI = (const float*)d_in[9];
  const float* W1   = (const float*)d_in[10];
  const float* b1   = (const float*)d_in[11];
  const float* W2   = (const float*)d_in[12];
  const float* b2   = (const float*)d_in[13];
  const float* Wu   = (const float*)d_in[14];
  const float* bu   = (const float*)d_in[15];
  const float* Wr   = (const float*)d_in[16];
  const float* br   = (const float*)d_in[17];
  const float* Wc   = (const float*)d_in[18];
  const float* bc   = (const float*)d_in[19];
  float* out = (float*)d_out;
  float* ws  = (float*)d_ws;
  // zero flags + h state every launch (ws is poisoned 0xAA)
  hipMemsetAsync((char*)d_ws + WS_FLG*sizeof(float), 0, 4352*sizeof(unsigned), stream);
  hipMemsetAsync((char*)d_ws + WS_H*sizeof(float), 0, 262144*sizeof(float), stream);
  k_vv  <<<128, 256, 0, stream>>>(vpe, W1, b1, W2, b2, ws);
  k_fold<<<384, 256, 0, stream>>>(Wr, Wu, Wc, br, bu, bc, ws);
  k_tot <<<16,  256, 0, stream>>>(maskp, ws);
  k_rs  <<<1024,256, 0, stream>>>(avg, ws);
  for (int c = 0; c < 4; c++){
    int c0 = c*16;
    p4a <<<512, 256, 0, stream>>>(obs, maskp, adjI, rW, lens, ws, c0);
    p4b <<<1536,256, 0, stream>>>(obs, lens, ws, c0);
    krec<<<512, 256, 0, stream>>>(maskp, lens, adjI, rW, out, ws, c0);
  }
}

// Round 8
// 1529.480 us; speedup vs baseline: 1.1954x; 1.1954x over previous
//
#include <hip/hip_runtime.h>
#include <math.h>

// Problem constants: B=32, T=64, N=128, D=64, E=5.  Time chunked: TC=16, 4 chunks.
// Workspace layout (float element offsets)
constexpr size_t WS_VV  = 1024;
constexpr size_t WS_TOT = 2048;
constexpr size_t WS_RS  = 8192;                  // 262144
constexpr size_t WS_WH  = 270336;                // 3*128*64*64 = 1572864 (Wr|Wu|Wc h-part)
constexpr size_t WS_WX  = 1843200;               // 3*128*65*64 = 1597440
constexpr size_t WS_BF  = 3440640;               // 3*128*64
constexpr size_t WS_H   = 3465216;               // 262144 (recurrent state; MALL-coherent)
constexpr size_t WS_CH  = 3727360;               // 262144 (combH exchange; MALL-coherent)
constexpr size_t WS_CX  = 3989504;               // 128*512*65 = 4259840   [n][b*16+tl][65]
constexpr size_t WS_GXR = 8249344;               // 128*16*32*64 = 4194304 [n][tl][b][o]
constexpr size_t WS_GXU = 12443648;
constexpr size_t WS_CXC = 16637952;
constexpr size_t WS_FLG = 20832256;              // flags: cfl[256] | hfl2[4096] (uint32)
// end = 20836608 floats = 79.5 MiB

__device__ __forceinline__ float sigm(float x){ return 1.f/(1.f+expf(-x)); }

// MALL-coherent (agent-scope relaxed => sc0 sc1, no cache maintenance) 8B ld/st
__device__ __forceinline__ float2 ld2_mall(const float* p){
  union { unsigned long long u; float2 f; } cv;
  cv.u = __hip_atomic_load((const unsigned long long*)p, __ATOMIC_RELAXED,
                           __HIP_MEMORY_SCOPE_AGENT);
  return cv.f;
}
__device__ __forceinline__ void st2_mall(float* p, float a, float b){
  union { unsigned long long u; float2 f; } cv;
  cv.f = make_float2(a, b);
  __hip_atomic_store((unsigned long long*)p, cv.u, __ATOMIC_RELAXED,
                     __HIP_MEMORY_SCOPE_AGENT);
}
__device__ __forceinline__ unsigned ldflag(const unsigned* p){
  return __hip_atomic_load(p, __ATOMIC_RELAXED, __HIP_MEMORY_SCOPE_AGENT);
}
__device__ __forceinline__ void stflag(unsigned* p, unsigned v){
  __hip_atomic_store(p, v, __ATOMIC_RELAXED, __HIP_MEMORY_SCOPE_AGENT);
}

// nontemporal helpers (read-once / write-once streams; keep L2 for hot data)
typedef float vf4 __attribute__((ext_vector_type(4)));
__device__ __forceinline__ float4 ntld4(const float* p){
  vf4 v = __builtin_nontemporal_load((const vf4*)p);
  return make_float4(v.x, v.y, v.z, v.w);
}
__device__ __forceinline__ void ntst4(float* p, float4 o){
  vf4 v; v.x=o.x; v.y=o.y; v.z=o.z; v.w=o.w;
  __builtin_nontemporal_store(v, (vf4*)p);
}

// ---------------- vv = relu(vpe@W1+b1)@W2+b2 ----------------
__global__ void k_vv(const float* __restrict__ vpe, const float* __restrict__ W1,
                     const float* __restrict__ b1, const float* __restrict__ W2,
                     const float* __restrict__ b2, float* __restrict__ ws){
  int n = blockIdx.x, tid = threadIdx.x;
  __shared__ float hid[128];
  if (tid < 128){
    float acc = b1[tid];
    for (int k=0;k<768;k++) acc = fmaf(vpe[n*768+k], W1[k*128+tid], acc);
    hid[tid] = fmaxf(acc, 0.f);
  }
  __syncthreads();
  if (tid < 5){
    float acc = b2[tid];
    for (int h=0;h<128;h++) acc = fmaf(hid[h], W2[h*5+tid], acc);
    ws[WS_VV + n*5 + tid] = acc;
  }
}

// ---------------- fold per-node weights: Wn = sum_e vv[n,e]*W[e] ----------------
__global__ void k_fold(const float* __restrict__ Wr, const float* __restrict__ Wu,
                       const float* __restrict__ Wc, const float* __restrict__ br,
                       const float* __restrict__ bu, const float* __restrict__ bc,
                       float* __restrict__ ws){
  int bid = blockIdx.x; int g = bid>>7; int n = bid&127;
  const float* W  = (g==0)?Wr:(g==1)?Wu:Wc;
  const float* bb = (g==0)?br:(g==1)?bu:bc;
  float v[5];
#pragma unroll
  for (int e=0;e<5;e++) v[e] = ws[WS_VV + n*5 + e];
  for (int idx=threadIdx.x; idx<129*64; idx+=256){
    int i = idx>>6, o = idx&63;
    float a = 0.f;
#pragma unroll
    for (int e=0;e<5;e++) a = fmaf(v[e], W[(e*129+i)*64+o], a);
    if (i < 65) ws[WS_WX + (size_t)(g*128+n)*4160 + i*64 + o] = a;
    else        ws[WS_WH + (size_t)(g*128+n)*4096 + (i-65)*64 + o] = a;
  }
  if (threadIdx.x < 64){
    int o = threadIdx.x; float a = 0.f;
#pragma unroll
    for (int e=0;e<5;e++) a = fmaf(v[e], bb[e*64+o], a);
    ws[WS_BF + (g*128+n)*64 + o] = a;
  }
}

// ---------------- tot[b,n] = sum_t mask ----------------
__global__ void k_tot(const float* __restrict__ mask, float* __restrict__ ws){
  int id = blockIdx.x*256 + threadIdx.x;     // 4096
  int b = id>>7, n = id&127;
  float s = 0.f;
  for (int t=0;t<64;t++) s += mask[(b*64+t)*128 + n];
  ws[WS_TOT + b*128 + n] = s;
}

// ---------------- rs = 0.5*tanh(avg/(tot+1)) ----------------
__global__ void k_rs(const float* __restrict__ avg, float* __restrict__ ws){
  int id = blockIdx.x*256 + threadIdx.x;     // 262144
  int b = id>>13, n = id&127;
  float tot = ws[WS_TOT + b*128 + n];
  ws[WS_RS + id] = 0.5f * tanhf(avg[id] / (tot + 1.f));
}

// ---------------- P4a (per chunk): combX = adj @ xtilde, stored [i][b*16+tl][65] ----------------
__global__ __launch_bounds__(256) void p4a(const float* __restrict__ obs,
      const float* __restrict__ mask, const float* __restrict__ adjI,
      const float* __restrict__ rW, const int* __restrict__ lengths,
      float* __restrict__ ws, int c0){
  int rc = blockIdx.x;                 // b*16 + tl
  int b = rc>>4, tl = rc&15, t = c0 + tl;
  if (t >= lengths[b]) return;
  int rt = b*64 + t;
  __shared__ float xt[64*68];
  __shared__ float adjh[128*68];
  __shared__ float rs_l[128], m_l[128];
  int tid = threadIdx.x;
  if (tid < 128){ rs_l[tid] = ws[WS_RS + rt*128 + tid]; m_l[tid] = mask[rt*128 + tid]; }
  __syncthreads();
  int it = tid>>3, ft = tid&7, i0 = it*4, f0 = ft*8;
  float4 aL[4], aH[4]; float a64[4];
#pragma unroll
  for (int ii=0;ii<4;ii++){ aL[ii]=make_float4(0,0,0,0); aH[ii]=make_float4(0,0,0,0); a64[ii]=0.f; }
  for (int half=0; half<2; half++){
    __syncthreads();
    int j0 = half*64;
    for (int idx=tid; idx<4096; idx+=256){
      int jl = idx>>6, f = idx&63;
      xt[jl*68+f] = obs[(size_t)rt*8192 + (j0+jl)*64 + f];
    }
    if (tid < 64) xt[tid*68+64] = rs_l[j0+tid];
    for (int idx=tid; idx<8192; idx+=256){
      int i = idx>>6, jl = idx&63, j = j0+jl;
      float a;
      if (i == j) a = 1.f;
      else {
        int gi = i*128 + j;
        float dd = fabsf(rs_l[i] - rs_l[j]);
        a = adjI[gi] * (1.f - rW[gi]*dd) * m_l[i] * m_l[j];
      }
      adjh[i*68+jl] = a;
    }
    __syncthreads();
    for (int jb=0; jb<16; jb++){
      float4 av[4];
#pragma unroll
      for (int ii=0;ii<4;ii++) av[ii] = *(const float4*)&adjh[(i0+ii)*68 + jb*4];
#pragma unroll
      for (int jj=0;jj<4;jj++){
        int jl = jb*4 + jj;
        float4 xlo = *(const float4*)&xt[jl*68 + f0];
        float4 xhi = *(const float4*)&xt[jl*68 + f0 + 4];
        float xr = xt[jl*68 + 64];
#pragma unroll
        for (int ii=0;ii<4;ii++){
          float a = (jj==0)?av[ii].x:(jj==1)?av[ii].y:(jj==2)?av[ii].z:av[ii].w;
          aL[ii].x = fmaf(a, xlo.x, aL[ii].x); aL[ii].y = fmaf(a, xlo.y, aL[ii].y);
          aL[ii].z = fmaf(a, xlo.z, aL[ii].z); aL[ii].w = fmaf(a, xlo.w, aL[ii].w);
          aH[ii].x = fmaf(a, xhi.x, aH[ii].x); aH[ii].y = fmaf(a, xhi.y, aH[ii].y);
          aH[ii].z = fmaf(a, xhi.z, aH[ii].z); aH[ii].w = fmaf(a, xhi.w, aH[ii].w);
          a64[ii] = fmaf(a, xr, a64[ii]);
        }
      }
    }
  }
#pragma unroll
  for (int ii=0;ii<4;ii++){
    int i = i0 + ii;
    size_t base = WS_CX + (size_t)i*33280 + (size_t)rc*65 + f0;
    ws[base+0]=aL[ii].x; ws[base+1]=aL[ii].y; ws[base+2]=aL[ii].z; ws[base+3]=aL[ii].w;
    ws[base+4]=aH[ii].x; ws[base+5]=aH[ii].y; ws[base+6]=aH[ii].z; ws[base+7]=aH[ii].w;
    if (ft == 0) ws[WS_CX + (size_t)i*33280 + (size_t)rc*65 + 64] = a64[ii];
  }
}

// ---------------- P4b (per chunk): per-node GEMMs for x-part of gates (incl. bias) ----------------
__global__ __launch_bounds__(256) void p4b(const float* __restrict__ obs,
      const int* __restrict__ lengths, float* __restrict__ ws, int c0){
  int bid = blockIdx.x;                 // 1536 = 3 * 128 * 4
  int g = bid >> 9; int r2 = bid & 511; int n = r2 >> 2; int tile = r2 & 3;
  __shared__ float A[128*69];
  __shared__ float Wl[65*64];
  __shared__ float bl[64];
  __shared__ int slen[32];
  int tid = threadIdx.x;
  if (tid < 32) slen[tid] = lengths[tid];
  for (int idx=tid; idx<4160; idx+=256) Wl[idx] = ws[WS_WX + (size_t)(g*128+n)*4160 + idx];
  if (tid < 64) bl[tid] = ws[WS_BF + (g*128+n)*64 + tid];
  if (g < 2){
    const float* src = &ws[WS_CX + (size_t)n*33280 + (size_t)tile*8320];
    for (int idx=tid; idx<8320; idx+=256){
      int r = idx/65, f = idx - r*65;
      A[r*69+f] = src[idx];
    }
  } else {
    for (int idx=tid; idx<8320; idx+=256){
      int r = idx/65, f = idx - r*65;
      int grow = tile*128 + r;              // b*16+tl
      int gb = grow>>4, t = c0 + (grow&15);
      float v = (f < 64) ? obs[(size_t)(gb*64+t)*8192 + n*64 + f]
                         : ws[WS_RS + (gb*64+t)*128 + n];
      A[r*69+f] = v;
    }
  }
  __syncthreads();
  int rt8 = tid>>4, dq = tid&15;
  float4 acc[8];
#pragma unroll
  for (int rr=0;rr<8;rr++) acc[rr] = make_float4(0,0,0,0);
  for (int k=0;k<65;k++){
    float4 w = *(const float4*)&Wl[k*64 + dq*4];
#pragma unroll
    for (int rr=0;rr<8;rr++){
      float a = A[(rt8*8+rr)*69 + k];
      acc[rr].x = fmaf(a,w.x,acc[rr].x); acc[rr].y = fmaf(a,w.y,acc[rr].y);
      acc[rr].z = fmaf(a,w.z,acc[rr].z); acc[rr].w = fmaf(a,w.w,acc[rr].w);
    }
  }
  float4 b4 = *(const float4*)&bl[dq*4];
  float* dst = &ws[(g==0)?WS_GXR:(g==1)?WS_GXU:WS_CXC];
#pragma unroll
  for (int rr=0;rr<8;rr++){
    int grow = tile*128 + rt8*8 + rr;
    int gb = grow>>4, gtl = grow&15;
    if (c0 + gtl < slen[gb]){
      float4 o; o.x=acc[rr].x+b4.x; o.y=acc[rr].y+b4.y; o.z=acc[rr].z+b4.z; o.w=acc[rr].w+b4.w;
      ntst4(&dst[((size_t)(n*16+gtl)*32 + gb)*64 + dq*4], o);   // read-once stream
    }
  }
}

// ---------------- Recurrent persistent kernel v8 (wave-autonomous B, per chunk) ----------------
// 512 blocks x 256 threads (any 2 fit one CU: A=60KB, B=58KB LDS).
//  bid<256: A-block (bA=bid>>3, slice sA=bid&7), block-cooperative (batch-local only):
//    adj rows (adjI/rW cached), poll hfl2[bA][0..128), stage h, combH rows -> chbuf,
//    drain, cfl[bA*8+sA]=t+1.
//  bid>=256: B-block (nB, half hf): weights in LDS (one barrier), then FOUR AUTONOMOUS
//    WAVES, wave = (node nB, 4 batches): poll 4 cfl flags, per-wave LDS strips for
//    combH/h1 (same-wave LDS ordering + lgkmcnt asm, NO block barriers), gate GEMMs,
//    wave-level vmcnt(0) drain, per-(batch,node) flags hfl2[bb*128+nB]=t+1.
// Cross-block data via MALL (sc0 sc1); plain monotone flags; zero global atomics.
__global__ __launch_bounds__(256) void krec(const float* __restrict__ mask,
      const int* __restrict__ lengths, const float* __restrict__ adjI,
      const float* __restrict__ rWm, float* __restrict__ out, float* __restrict__ ws,
      int c0){
  unsigned* cfl  = (unsigned*)(ws + WS_FLG);         // [b*8+s]
  unsigned* hfl2 = ((unsigned*)(ws + WS_FLG)) + 256; // [b*128+n]
  const int bid = blockIdx.x, tid = threadIdx.x;
  __shared__ float smem[15104];                      // 60416 B
  float* hbuf = &ws[WS_H];
  float* chb  = &ws[WS_CH];

  if (bid < 256){
    // ================= A-role (block-cooperative, batch-local) =================
    const int bA = bid>>3, sA = bid&7, ns = sA*16;
    float* hs   = smem;            // 8192
    float* adjT = smem + 8192;     // [j][r] stride 20 -> 2560
    float* adjS = smem + 10752;    // 2048 cached adjI slice
    float* rWS  = smem + 12800;    // 2048 cached rarity_W slice
    float* rs_l = smem + 14848;    // 128
    float* m_l  = smem + 14976;    // 128
    const int lenA = lengths[bA];
    if (c0 >= lenA) return;
    for (int idx=tid; idx<2048; idx+=256){
      int gi = (ns + (idx>>7))*128 + (idx&127);
      adjS[idx] = adjI[gi];
      rWS[idx]  = rWm[gi];
    }
    const int pr = tid>>4, fq = tid&15;   // row ns+pr, features fq*4..+4
    const int tEnd = (lenA < c0+16) ? lenA : (c0+16);
    __syncthreads();
    for (int t=c0; t<tEnd; t++){
      if (tid < 128) rs_l[tid] = ws[WS_RS + (size_t)(bA*64+t)*128 + tid];
      else           m_l[tid-128] = mask[(size_t)(bA*64+t)*128 + (tid-128)];
      __syncthreads();                              // rs/m ready
      for (int idx=tid; idx<2048; idx+=256){
        int r = idx>>7, j = idx&127, I = ns+r;
        float a;
        if (I == j) a = 1.f;
        else {
          float dd = fabsf(rs_l[I] - rs_l[j]);
          a = adjS[idx]*(1.f - rWS[idx]*dd)*m_l[I]*m_l[j];
        }
        adjT[j*20 + r] = a;
      }
      if (tid < 128){                               // poll own batch's node flags
        unsigned tgt = (unsigned)t; int guard = 0;
        while (ldflag(&hfl2[bA*128 + tid]) < tgt && ++guard < (1<<20))
          __builtin_amdgcn_s_sleep(1);
      }
      __syncthreads();                              // adjT + poll done
#pragma unroll
      for (int k2=0;k2<16;k2++){
        int p = tid + 256*k2;
        float2 v = ld2_mall(&hbuf[(size_t)bA*8192 + 2*p]);
        *(float2*)&hs[2*p] = v;
      }
      __syncthreads();                              // hs ready
      {
        float4 acc = make_float4(0,0,0,0);
#pragma unroll 4
        for (int j=0;j<128;j++){
          float aj = adjT[j*20 + pr];
          float4 h4 = *(const float4*)&hs[j*64 + fq*4];
          acc.x = fmaf(aj,h4.x,acc.x); acc.y = fmaf(aj,h4.y,acc.y);
          acc.z = fmaf(aj,h4.z,acc.z); acc.w = fmaf(aj,h4.w,acc.w);
        }
        float* cp = &chb[((size_t)bA*128 + ns + pr)*64 + fq*4];
        st2_mall(cp,   acc.x, acc.y);
        st2_mall(cp+2, acc.z, acc.w);
      }
      asm volatile("s_waitcnt vmcnt(0)" ::: "memory");
      __syncthreads();                              // all combH stores drained
      if (tid == 0)
        stflag(&cfl[bA*8 + sA], (unsigned)(t+1));
    }
  } else {
    // ================= B-role (wave-autonomous) =================
    const int nB = (bid-256)>>1, hf = (bid-256)&1;
    float* wR = smem;              // 4096
    float* wU = smem + 4096;       // 4096
    float* wC = smem + 8192;       // 4096
    float* strips = smem + 12288;  // 4 waves x 576
    for (int idx=tid; idx<3072; idx+=256){
      int g = idx>>10, r = idx&1023;
      *(float4*)&smem[g*4096 + r*4] =
        *(const float4*)&ws[WS_WH + (size_t)(g*128+nB)*4096 + (size_t)r*4];
    }
    __syncthreads();               // weights ready — ONLY block barrier
    const int wv = tid>>6, ln = tid&63;
    const int bi = ln>>4, fq = ln&15;
    const int bb = hf*16 + wv*4 + bi;
    const int slenB = lengths[bb];
    const int sIdx = nB>>4;
    float* cw = strips + wv*576;   // [bi*72 + k], 288 floats
    float* hw = cw + 288;          // [bi*72 + k], 288 floats
    unsigned* cflp = &cfl[bb*8 + sIdx];
    float4 hst;
    { const float* hp = &hbuf[((size_t)bb*128+nB)*64 + fq*4];
      float2 lo = ld2_mall(hp), hi = ld2_mall(hp+2);
      hst = make_float4(lo.x, lo.y, hi.x, hi.y); }

    for (int t=c0; t<c0+16; t++){
      const bool alive = (t < slenB);
      if (__ballot(alive) == 0ULL) break;           // whole wave done
      const int tl = t - c0;
      float4 xr, xu, xc; float mv = 0.f;
      if (alive){                                   // read-once NT prefetch
        size_t gof = ((size_t)(nB*16+tl)*32 + bb)*64 + fq*4;
        xr = ntld4(&ws[WS_GXR + gof]);
        xu = ntld4(&ws[WS_GXU + gof]);
        xc = ntld4(&ws[WS_CXC + gof]);
        mv = mask[(size_t)(bb*64+t)*128 + nB];
      }
      if (alive && fq == 0){                        // 4 lanes poll their batch flag
        unsigned tgt = (unsigned)(t+1); int guard = 0;
        while (ldflag(cflp) < tgt && ++guard < (1<<20))
          __builtin_amdgcn_s_sleep(1);
      }
      asm volatile("" ::: "memory");                // no hoisting across the poll
      if (alive){                                   // combH row -> per-wave strip
        const float* cp = &chb[((size_t)bb*128 + nB)*64 + fq*4];
        float2 u = ld2_mall(cp), v = ld2_mall(cp+2);
        *(float4*)&cw[bi*72 + fq*4] = make_float4(u.x, u.y, v.x, v.y);
      }
      asm volatile("s_waitcnt lgkmcnt(0)" ::: "memory");  // same-wave LDS order
      float4 uu, h1v; bool ob = mv > 0.f;
      if (alive){
        float4 ar = xr, au = xu;
#pragma unroll 4
        for (int k=0;k<64;k++){
          float cv = cw[bi*72 + k];
          float4 wr4 = *(const float4*)&wR[k*64 + fq*4];
          float4 wu4 = *(const float4*)&wU[k*64 + fq*4];
          ar.x = fmaf(cv,wr4.x,ar.x); ar.y = fmaf(cv,wr4.y,ar.y);
          ar.z = fmaf(cv,wr4.z,ar.z); ar.w = fmaf(cv,wr4.w,ar.w);
          au.x = fmaf(cv,wu4.x,au.x); au.y = fmaf(cv,wu4.y,au.y);
          au.z = fmaf(cv,wu4.z,au.z); au.w = fmaf(cv,wu4.w,au.w);
        }
        float4 rr;
        rr.x = sigm(ar.x); rr.y = sigm(ar.y); rr.z = sigm(ar.z); rr.w = sigm(ar.w);
        uu.x = sigm(au.x); uu.y = sigm(au.y); uu.z = sigm(au.z); uu.w = sigm(au.w);
        h1v.x = ob ? rr.x*hst.x : hst.x;
        h1v.y = ob ? rr.y*hst.y : hst.y;
        h1v.z = ob ? rr.z*hst.z : hst.z;
        h1v.w = ob ? rr.w*hst.w : hst.w;
        *(float4*)&hw[bi*72 + fq*4] = h1v;
      }
      asm volatile("s_waitcnt lgkmcnt(0)" ::: "memory");  // h1 strip visible in-wave
      if (alive){
        float4 ac = xc;
#pragma unroll 4
        for (int k=0;k<64;k++){
          float hv = hw[bi*72 + k];
          float4 wc4 = *(const float4*)&wC[k*64 + fq*4];
          ac.x = fmaf(hv,wc4.x,ac.x); ac.y = fmaf(hv,wc4.y,ac.y);
          ac.z = fmaf(hv,wc4.z,ac.z); ac.w = fmaf(hv,wc4.w,ac.w);
        }
        float4 cd, h2;
        cd.x = tanhf(ac.x); cd.y = tanhf(ac.y); cd.z = tanhf(ac.z); cd.w = tanhf(ac.w);
        h2.x = ob ? (1.f-uu.x)*h1v.x + uu.x*cd.x : h1v.x;
        h2.y = ob ? (1.f-uu.y)*h1v.y + uu.y*cd.y : h1v.y;
        h2.z = ob ? (1.f-uu.z)*h1v.z + uu.z*cd.z : h1v.z;
        h2.w = ob ? (1.f-uu.w)*h1v.w + uu.w*cd.w : h1v.w;
        hst = h2;
        float* hp = &hbuf[((size_t)bb*128 + nB)*64 + fq*4];
        st2_mall(hp,   h2.x, h2.y);
        st2_mall(hp+2, h2.z, h2.w);
        if (t == slenB-1)
          *(float4*)&out[((size_t)bb*128 + nB)*64 + fq*4] = h2;
      }
      asm volatile("s_waitcnt vmcnt(0)" ::: "memory");    // wave-level drain
      if (alive && fq == 0)
        stflag(&hfl2[bb*128 + nB], (unsigned)(t+1));
    }
  }
}

extern "C" void kernel_launch(void* const* d_in, const int* in_sizes, int n_in,
                              void* d_out, int out_size, void* d_ws, size_t ws_size,
                              hipStream_t stream){
  const float* obs  = (const float*)d_in[0];
  const float* maskp= (const float*)d_in[2];
  const int*   lens = (const int*)d_in[5];
  const float* avg  = (const float*)d_in[6];
  const float* vpe  = (const float*)d_in[7];
  const float* rW   = (const float*)d_in[8];
  const float* adjI = (const float*)d_in[9];
  const float* W1   = (const float*)d_in[10];
  const float* b1   = (const float*)d_in[11];
  const float* W2   = (const float*)d_in[12];
  const float* b2   = (const float*)d_in[13];
  const float* Wu   = (const float*)d_in[14];
  const float* bu   = (const float*)d_in[15];
  const float* Wr   = (const float*)d_in[16];
  const float* br   = (const float*)d_in[17];
  const float* Wc   = (const float*)d_in[18];
  const float* bc   = (const float*)d_in[19];
  float* out = (float*)d_out;
  float* ws  = (float*)d_ws;
  // zero flags + h state every launch (ws is poisoned 0xAA)
  hipMemsetAsync((char*)d_ws + WS_FLG*sizeof(float), 0, 4352*sizeof(unsigned), stream);
  hipMemsetAsync((char*)d_ws + WS_H*sizeof(float), 0, 262144*sizeof(float), stream);
  k_vv  <<<128, 256, 0, stream>>>(vpe, W1, b1, W2, b2, ws);
  k_fold<<<384, 256, 0, stream>>>(Wr, Wu, Wc, br, bu, bc, ws);
  k_tot <<<16,  256, 0, stream>>>(maskp, ws);
  k_rs  <<<1024,256, 0, stream>>>(avg, ws);
  for (int c = 0; c < 4; c++){
    int c0 = c*16;
    p4a <<<512, 256, 0, stream>>>(obs, maskp, adjI, rW, lens, ws, c0);
    p4b <<<1536,256, 0, stream>>>(obs, lens, ws, c0);
    krec<<<512, 256, 0, stream>>>(maskp, lens, adjI, rW, out, ws, c0);
  }
}